// Round 6
// baseline (756.868 us; speedup 1.0000x reference)
//
#include <hip/hip_runtime.h>
#include <hip/hip_bf16.h>
#include <math.h>

typedef unsigned short u16;
typedef __attribute__((ext_vector_type(8))) short bf16x8;
typedef __attribute__((ext_vector_type(4))) float f32x4;

// ---------- helpers ----------
__device__ __forceinline__ u16 f2bf(float f) {
  union { float f; unsigned u; } x; x.f = f;
  unsigned r = x.u + 0x7fffu + ((x.u >> 16) & 1u);
  return (u16)(r >> 16);
}
__device__ __forceinline__ float bf2f(u16 h) {
  union { unsigned u; float f; } x; x.u = ((unsigned)h) << 16;
  return x.f;
}
__device__ __forceinline__ float sigmf(float x) {
  x = fminf(fmaxf(x, -30.f), 30.f);
  return 1.f / (1.f + __expf(-x));
}
__device__ __forceinline__ float tanh_fast(float x) {
  x = fminf(fmaxf(x, -15.f), 15.f);
  float t = __expf(2.f * x);
  return (t - 1.f) / (t + 1.f);
}

// ---------- problem constants ----------
#define NB 4
#define DE 128
#define DO_ 512
#define HW 1560
#define THW 6240
#define NP 1664   // HW padded to 13*128
#define KP 6272   // THW padded to 49*128
#define PROP 5
#define PVSPLIT 7
#define PVKC 896  // 6272/7 = 28*32

// ================= scores GEMM (K=128): Pt = exp(qiT @ miT^T * s) ==========
// A-panel 64x128 staged to LDS once; B (miT rows) streamed to regs.
__global__ __launch_bounds__(256)
void gemm_scores(const u16* __restrict__ qiT, const u16* __restrict__ miT,
                 float* __restrict__ Zp, u16* __restrict__ Pt)
{
  __shared__ u16 lds[1024][8];             // slot = g*64 + row (g = k/8)
  const int tid = threadIdx.x;
  const int wave = tid >> 6, lane = tid & 63;
  const int kg = lane >> 4, lr = lane & 15;
  const long b = blockIdx.z;
  const int m0 = blockIdx.x * 64, n0 = blockIdx.y * 128;
  const u16* A = qiT + b * ((long)NP * DE);
  const u16* Bt = miT + b * ((long)KP * DE);

#pragma unroll
  for (int i = 0; i < 4; ++i) {
    int s = tid + 256 * i;
    int row = s & 63, g = s >> 6;
    const u16* src = A + (long)(m0 + row) * DE + g * 8;
    __builtin_amdgcn_global_load_lds(
        (const __attribute__((address_space(1))) void*)src,
        (__attribute__((address_space(3))) void*)&lds[wave * 64 + 256 * i][0],
        16, 0, 0);
  }
  __syncthreads();

  f32x4 acc[4][2];
#pragma unroll
  for (int m = 0; m < 4; ++m)
#pragma unroll
    for (int n = 0; n < 2; ++n) acc[m][n] = (f32x4){0.f, 0.f, 0.f, 0.f};

  const u16* Bp0 = Bt + (long)(n0 + wave * 32 + lr) * DE + kg * 8;
  const u16* Bp1 = Bp0 + 16 * DE;
#pragma unroll
  for (int g2 = 0; g2 < 4; ++g2) {
    bf16x8 af[4], bf[2];
#pragma unroll
    for (int m = 0; m < 4; ++m)
      af[m] = *(const bf16x8*)&lds[(g2 * 4 + kg) * 64 + m * 16 + lr][0];
    bf[0] = *(const bf16x8*)&Bp0[g2 * 32];
    bf[1] = *(const bf16x8*)&Bp1[g2 * 32];
#pragma unroll
    for (int m = 0; m < 4; ++m)
#pragma unroll
      for (int n = 0; n < 2; ++n)
        acc[m][n] = __builtin_amdgcn_mfma_f32_16x16x32_bf16(af[m], bf[n], acc[m][n], 0, 0, 0);
  }

  const float scale = 0.08838834764831845f;
  float rs[4][4];
#pragma unroll
  for (int m = 0; m < 4; ++m)
#pragma unroll
    for (int j = 0; j < 4; ++j) rs[m][j] = 0.f;
#pragma unroll
  for (int m = 0; m < 4; ++m) {
#pragma unroll
    for (int n = 0; n < 2; ++n) {
      int col = n0 + wave * 32 + n * 16 + lr;
#pragma unroll
      for (int j = 0; j < 4; ++j) {
        long row = m0 + m * 16 + kg * 4 + j;
        float p = __expf(acc[m][n][j] * scale);
        bool valid = (col < THW);
        Pt[b * ((long)NP * KP) + row * KP + col] = valid ? f2bf(p) : (u16)0;
        rs[m][j] += valid ? p : 0.f;
      }
    }
  }
#pragma unroll
  for (int m = 0; m < 4; ++m)
#pragma unroll
    for (int j = 0; j < 4; ++j) {
#pragma unroll
      for (int msk = 1; msk < 16; msk <<= 1)
        rs[m][j] += __shfl_xor(rs[m][j], msk, 64);
    }
  __syncthreads();
  float* zbuf = (float*)&lds[0][0];
  if (lr == 0) {
#pragma unroll
    for (int m = 0; m < 4; ++m)
#pragma unroll
      for (int j = 0; j < 4; ++j)
        zbuf[wave * 64 + m * 16 + kg * 4 + j] = rs[m][j];
  }
  __syncthreads();
  if (tid < 64)
    Zp[b * ((long)49 * NP) + (long)blockIdx.y * NP + (m0 + tid)] =
        zbuf[tid] + zbuf[64 + tid] + zbuf[128 + tid] + zbuf[192 + tid];
}

// ========== mem GEMM: Ppart[b,z] = Pt(k-chunk z) @ moutb^T, BN=512 =========
// 728 blocks, XCD-pinned decode: same (b,z) pair's 26 m-blocks share an XCD
// so the B-slice + A rows stay in that XCD's L2.
__global__ __launch_bounds__(256, 2)
void gemm_pv(const u16* __restrict__ Pt, const u16* __restrict__ moutb,
             u16* __restrict__ Ppart)
{
  const int bid = blockIdx.x;            // 0..727
  const int xcd = bid & 7, i = bid >> 3; // i 0..90
  const int s = xcd * 91 + i;            // 0..727
  const int pair = s / 26, mb = s - pair * 26;
  const int b = pair / PVSPLIT, z = pair - b * PVSPLIT;
  const int m0 = mb * 64;
  const int k0 = z * PVKC;               // 28 steps of 32

  const u16* A = Pt + (long)b * NP * KP;
  const u16* B0;
  {
    const u16* Bb = moutb + (long)b * DO_ * KP;
    B0 = Bb + (long)((threadIdx.x >> 6) * 128 + (threadIdx.x & 15)) * KP +
         ((threadIdx.x & 63) >> 4) * 8;
  }

  __shared__ u16 lds[2][2048];
  const int tid = threadIdx.x;
  const int wave = tid >> 6, lane = tid & 63;
  const int kg = lane >> 4, lr = lane & 15;

  auto stage = [&](int buf, int kt) {
    int row = tid & 63, g = tid >> 6;
    const u16* src = A + (long)(m0 + row) * KP + kt + g * 8;
    __builtin_amdgcn_global_load_lds(
        (const __attribute__((address_space(1))) void*)src,
        (__attribute__((address_space(3))) void*)&lds[buf][(wave * 64) * 8],
        16, 0, 0);
  };

  f32x4 acc[4][8];
#pragma unroll
  for (int m = 0; m < 4; ++m)
#pragma unroll
    for (int n = 0; n < 8; ++n) acc[m][n] = (f32x4){0.f, 0.f, 0.f, 0.f};

  bf16x8 bra[8], brb[8];
#pragma unroll
  for (int n = 0; n < 8; ++n)
    bra[n] = *(const bf16x8*)&B0[(long)n * 16 * KP + k0];
  stage(0, k0);
  __syncthreads();

#define PV_STEP(BU, BL, T, CUR)                                                  \
  {                                                                              \
    if ((T) + 1 < 28) {                                                          \
      int ktn = k0 + ((T) + 1) * 32;                                             \
      _Pragma("unroll") for (int n = 0; n < 8; ++n)                              \
          BL[n] = *(const bf16x8*)&B0[(long)n * 16 * KP + ktn];                  \
      stage((CUR) ^ 1, ktn);                                                     \
    }                                                                            \
    bf16x8 af[4];                                                                \
    _Pragma("unroll") for (int m = 0; m < 4; ++m)                                \
        af[m] = *(const bf16x8*)&lds[CUR][(kg * 64 + m * 16 + lr) * 8];          \
    _Pragma("unroll") for (int m = 0; m < 4; ++m)                                \
        _Pragma("unroll") for (int n = 0; n < 8; ++n)                            \
            acc[m][n] = __builtin_amdgcn_mfma_f32_16x16x32_bf16(af[m], BU[n],    \
                                                                acc[m][n], 0, 0, 0); \
    __syncthreads();                                                             \
  }

  for (int tp = 0; tp < 14; ++tp) {
    PV_STEP(bra, brb, 2 * tp, 0);
    PV_STEP(brb, bra, 2 * tp + 1, 1);
  }
#undef PV_STEP

  u16* out = Ppart + (long)(b * PVSPLIT + z) * NP * DO_;
#pragma unroll
  for (int m = 0; m < 4; ++m) {
#pragma unroll
    for (int n = 0; n < 8; ++n) {
      int col = wave * 128 + n * 16 + lr;
#pragma unroll
      for (int j = 0; j < 4; ++j) {
        int row = m0 + m * 16 + kg * 4 + j;
        out[(long)row * DO_ + col] = f2bf(acc[m][n][j]);
      }
    }
  }
}

// ========== fused 5-layer GRU chain (one dispatch) =========================
// 104 blocks x 512 threads; block owns 64 rows. x and r*h live in swizzled
// LDS across layers; weights streamed coalesced in MFMA-frag order from L2.
// Prologue also computes chru = mem @ W*h^T + bias (written once to global,
// re-read per layer, L2-hot).
__global__ __launch_bounds__(512, 2)
void gru_fused(const u16* __restrict__ qT, const u16* __restrict__ memTb,
               const u16* __restrict__ Wfu, const u16* __restrict__ Wfr,
               const u16* __restrict__ Wfuh, const u16* __restrict__ Wfrh,
               const u16* __restrict__ Wfc,
               const float* __restrict__ br_, const float* __restrict__ bu_,
               const float* __restrict__ bc_,
               u16* __restrict__ chru, float* __restrict__ Qfin)
{
  __shared__ u16 xs[64 * 512];
  __shared__ u16 rhs[64 * 512];
  const int tid = threadIdx.x;
  const int wave = tid >> 6, lane = tid & 63;
  const int kg = lane >> 4, lr = lane & 15;
  const int b = blockIdx.y;
  const int m0 = blockIdx.x * 64;

  const u16* qs = qT + ((long)b * NP + m0) * 512;
  const u16* msp = memTb + ((long)b * NP + m0) * 512;
  u16* chp = chru + ((long)b * NP + m0) * 1024;

  // stage xs <- q rows, rhs <- mem rows (16B-block XOR swizzle vs bank conflicts)
#pragma unroll
  for (int i = 0; i < 8; ++i) {
    int s = tid + 512 * i;
    int row = s >> 6, k8 = (s & 63) * 8;
    int di = row * 512 + (k8 ^ ((row & 7) << 3));
    *(uint4*)&xs[di] = *(const uint4*)&qs[row * 512 + k8];
    *(uint4*)&rhs[di] = *(const uint4*)&msp[row * 512 + k8];
  }
  __syncthreads();

  f32x4 au[4][4], ar[4][4];

#define GATES_LOOP(SRC, WU, WR)                                                 \
  _Pragma("unroll")                                                             \
  for (int m = 0; m < 4; ++m)                                                   \
    _Pragma("unroll")                                                           \
    for (int nf = 0; nf < 4; ++nf) {                                            \
      au[m][nf] = (f32x4){0.f, 0.f, 0.f, 0.f};                                  \
      ar[m][nf] = (f32x4){0.f, 0.f, 0.f, 0.f};                                  \
    }                                                                           \
  _Pragma("unroll 2")                                                           \
  for (int kt = 0; kt < 16; ++kt) {                                             \
    bf16x8 af[4], wu4[4], wr4[4];                                               \
    _Pragma("unroll")                                                           \
    for (int m = 0; m < 4; ++m) {                                               \
      int row = m * 16 + lr;                                                    \
      af[m] = *(const bf16x8*)&SRC[row * 512 +                                  \
                                   ((kt * 32 + kg * 8) ^ ((row & 7) << 3))];    \
    }                                                                           \
    _Pragma("unroll")                                                           \
    for (int nf = 0; nf < 4; ++nf) {                                            \
      long wo = (long)((kt * 32 + wave * 4 + nf) * 512 + lane * 8);             \
      wu4[nf] = *(const bf16x8*)&WU[wo];                                        \
      wr4[nf] = *(const bf16x8*)&WR[wo];                                        \
    }                                                                           \
    _Pragma("unroll")                                                           \
    for (int m = 0; m < 4; ++m)                                                 \
      _Pragma("unroll")                                                         \
      for (int nf = 0; nf < 4; ++nf) {                                          \
        au[m][nf] = __builtin_amdgcn_mfma_f32_16x16x32_bf16(af[m], wu4[nf],     \
                                                            au[m][nf], 0, 0, 0); \
        ar[m][nf] = __builtin_amdgcn_mfma_f32_16x16x32_bf16(af[m], wr4[nf],     \
                                                            ar[m][nf], 0, 0, 0); \
      }                                                                         \
  }

  // --- prologue: chru = mem @ W{r,u}h^T + bias (A = rhs holding mem) ---
  GATES_LOOP(rhs, Wfuh, Wfrh);
#pragma unroll
  for (int m = 0; m < 4; ++m)
#pragma unroll
    for (int nf = 0; nf < 4; ++nf) {
      int col = wave * 64 + nf * 16 + lr;
#pragma unroll
      for (int j = 0; j < 4; ++j) {
        int row = m * 16 + kg * 4 + j;
        chp[(long)row * 1024 + col] = f2bf(ar[m][nf][j] + br_[col]);
        chp[(long)row * 1024 + 512 + col] = f2bf(au[m][nf][j] + bu_[col]);
      }
    }
  __syncthreads();   // B0: all waves done reading rhs(mem) + chru drained

  for (int l = 0; l < PROP; ++l) {
    // --- gates: u and r share A reads ---
    GATES_LOOP(xs, Wfu, Wfr);
    unsigned u_pk[4][4][2];
#pragma unroll
    for (int m = 0; m < 4; ++m)
#pragma unroll
      for (int nf = 0; nf < 4; ++nf) {
        int col = wave * 64 + nf * 16 + lr;
#pragma unroll
        for (int p = 0; p < 2; ++p) {
          int r0 = m * 16 + kg * 4 + 2 * p;
          float uu0 = sigmf(au[m][nf][2 * p] + bf2f(chp[(long)r0 * 1024 + 512 + col]));
          float uu1 = sigmf(au[m][nf][2 * p + 1] + bf2f(chp[(long)(r0 + 1) * 1024 + 512 + col]));
          u_pk[m][nf][p] = (unsigned)f2bf(uu0) | ((unsigned)f2bf(uu1) << 16);
          float rr0 = sigmf(ar[m][nf][2 * p] + bf2f(chp[(long)r0 * 1024 + col]));
          float rr1 = sigmf(ar[m][nf][2 * p + 1] + bf2f(chp[(long)(r0 + 1) * 1024 + col]));
          float h0 = bf2f(msp[(long)r0 * 512 + col]);
          float h1 = bf2f(msp[(long)(r0 + 1) * 512 + col]);
          rhs[r0 * 512 + (col ^ ((r0 & 7) << 3))] = f2bf(rr0 * h0);
          rhs[(r0 + 1) * 512 + (col ^ (((r0 + 1) & 7) << 3))] = f2bf(rr1 * h1);
        }
      }
    __syncthreads();   // B1: rhs = r*h complete

    // --- candidate: K=1024 over [xs | rhs] ---
    f32x4 ac[4][4];
#pragma unroll
    for (int m = 0; m < 4; ++m)
#pragma unroll
      for (int nf = 0; nf < 4; ++nf) ac[m][nf] = (f32x4){0.f, 0.f, 0.f, 0.f};
#pragma unroll 2
    for (int kt = 0; kt < 16; ++kt) {
      bf16x8 af[4], wf4[4];
#pragma unroll
      for (int m = 0; m < 4; ++m) {
        int row = m * 16 + lr;
        af[m] = *(const bf16x8*)&xs[row * 512 + ((kt * 32 + kg * 8) ^ ((row & 7) << 3))];
      }
#pragma unroll
      for (int nf = 0; nf < 4; ++nf)
        wf4[nf] = *(const bf16x8*)&Wfc[(long)((kt * 32 + wave * 4 + nf) * 512 + lane * 8)];
#pragma unroll
      for (int m = 0; m < 4; ++m)
#pragma unroll
        for (int nf = 0; nf < 4; ++nf)
          ac[m][nf] = __builtin_amdgcn_mfma_f32_16x16x32_bf16(af[m], wf4[nf], ac[m][nf], 0, 0, 0);
    }
#pragma unroll 2
    for (int kt = 0; kt < 16; ++kt) {
      bf16x8 af[4], wf4[4];
#pragma unroll
      for (int m = 0; m < 4; ++m) {
        int row = m * 16 + lr;
        af[m] = *(const bf16x8*)&rhs[row * 512 + ((kt * 32 + kg * 8) ^ ((row & 7) << 3))];
      }
#pragma unroll
      for (int nf = 0; nf < 4; ++nf)
        wf4[nf] = *(const bf16x8*)&Wfc[(long)(((kt + 16) * 32 + wave * 4 + nf) * 512 + lane * 8)];
#pragma unroll
      for (int m = 0; m < 4; ++m)
#pragma unroll
        for (int nf = 0; nf < 4; ++nf)
          ac[m][nf] = __builtin_amdgcn_mfma_f32_16x16x32_bf16(af[m], wf4[nf], ac[m][nf], 0, 0, 0);
    }
    __syncthreads();   // B2: all waves done reading xs/rhs

    // --- GRU update epilogue ---
#pragma unroll
    for (int m = 0; m < 4; ++m)
#pragma unroll
      for (int nf = 0; nf < 4; ++nf) {
        int col = wave * 64 + nf * 16 + lr;
#pragma unroll
        for (int j = 0; j < 4; ++j) {
          int row = m * 16 + kg * 4 + j;
          float cg = tanh_fast(ac[m][nf][j] + bc_[col]);
          u16 uh = (u16)((j & 1) ? (u_pk[m][nf][j >> 1] >> 16)
                                 : (u_pk[m][nf][j >> 1] & 0xffff));
          float uu = bf2f(uh);
          float h = bf2f(msp[(long)row * 512 + col]);
          float xn = h * (1.f - uu) + uu * cg;
          if (l == PROP - 1)
            Qfin[((long)b * NP + m0 + row) * 512 + col] = xn;
          else
            xs[row * 512 + (col ^ ((row & 7) << 3))] = f2bf(xn);
        }
      }
    if (l < PROP - 1) __syncthreads();   // B3
  }
#undef GATES_LOOP
}

// ---------- small kernels ----------
// frag-order weight shuffle: dst[(kt*32+nb)*512 + lane*8 + e] =
//   bf16(src[(nb*16 + (lane&15)) * Ksrc + koff + kt*32 + (lane>>4)*8 + e])
__global__ void k_wfrag(const float* __restrict__ src, u16* __restrict__ dst,
                        int Ksrc, int koff) {
  int t = blockIdx.x * 256 + threadIdx.x;
  int e = t & 7, lane = (t >> 3) & 63, nb = (t >> 9) & 31, kt = t >> 14;
  int n = nb * 16 + (lane & 15);
  int k = koff + kt * 32 + (lane >> 4) * 8 + e;
  dst[t] = f2bf(src[(long)n * Ksrc + k]);
}

// transpose+cast: in f32 [R][C] -> out bf16 [Cp][out_ld], out[c][r]=in[r][c]
__global__ void k_transpose_cast(const float* __restrict__ in, u16* __restrict__ out,
                                 int R, int C, int Cp, int out_ld,
                                 long in_bs, long out_bs) {
  __shared__ float t[32][33];
  long b = blockIdx.z;
  int c0 = blockIdx.x * 32, r0 = blockIdx.y * 32;
  int tx = threadIdx.x, ty = threadIdx.y;
#pragma unroll
  for (int i = 0; i < 32; i += 8) {
    int r = r0 + ty + i, c = c0 + tx;
    t[ty + i][tx] = (r < R && c < C) ? in[b * in_bs + (long)r * C + c] : 0.f;
  }
  __syncthreads();
#pragma unroll
  for (int i = 0; i < 32; i += 8) {
    int c = c0 + ty + i, r = r0 + tx;
    if (c < Cp && r < R)
      out[b * out_bs + (long)c * out_ld + r] = f2bf(t[tx][ty + i]);
  }
}

// cast f32 [R][Cin] -> bf16 [R][Cout] with zero pad
__global__ void k_cast_pad(const float* __restrict__ in, u16* __restrict__ out,
                           int Cin, int Cout, long in_bs, long out_bs) {
  int c = blockIdx.x * 256 + threadIdx.x;
  int r = blockIdx.y;
  long b = blockIdx.z;
  if (c >= Cout) return;
  out[b * out_bs + (long)r * Cout + c] =
      (c < Cin) ? f2bf(in[b * in_bs + (long)r * Cin + c]) : (u16)0;
}

// invZ[b][q] = 1 / sum_nb Zp[b][nb][q]
__global__ void k_invz(const float* __restrict__ Zp, float* __restrict__ invZ) {
  int t = blockIdx.x * 256 + threadIdx.x;
  if (t >= NB * NP) return;
  int b = t / NP, q = t - b * NP;
  const float* base = Zp + (long)b * 49 * NP + q;
  float s = 0.f;
#pragma unroll
  for (int nb = 0; nb < 49; ++nb) s += base[(long)nb * NP];
  invZ[t] = 1.f / s;
}

// memTb[b][q][o] = bf16( invZ[b][q] * sum_z Ppart[b*PVSPLIT+z][q][o] )
__global__ void k_reduce_mem(const u16* __restrict__ Ppart, const float* __restrict__ invZ,
                             u16* __restrict__ memTb) {
  long t = (long)blockIdx.x * 256 + threadIdx.x;   // uint4 index (8 bf16)
  const long bs = (long)NP * DO_;
  if (t >= (long)NB * bs / 8) return;
  long flat = t * 8;
  int b = (int)(flat / bs);
  long r = flat - (long)b * bs;
  int q = (int)(r / DO_);
  float s[8];
#pragma unroll
  for (int e = 0; e < 8; ++e) s[e] = 0.f;
#pragma unroll
  for (int z = 0; z < PVSPLIT; ++z) {
    uint4 v = *(const uint4*)&Ppart[(long)(b * PVSPLIT + z) * bs + r];
    s[0] += bf2f((u16)(v.x & 0xffff)); s[1] += bf2f((u16)(v.x >> 16));
    s[2] += bf2f((u16)(v.y & 0xffff)); s[3] += bf2f((u16)(v.y >> 16));
    s[4] += bf2f((u16)(v.z & 0xffff)); s[5] += bf2f((u16)(v.z >> 16));
    s[6] += bf2f((u16)(v.w & 0xffff)); s[7] += bf2f((u16)(v.w >> 16));
  }
  float iz = invZ[b * NP + q];
  uint4 o;
  o.x = (unsigned)f2bf(s[0] * iz) | ((unsigned)f2bf(s[1] * iz) << 16);
  o.y = (unsigned)f2bf(s[2] * iz) | ((unsigned)f2bf(s[3] * iz) << 16);
  o.z = (unsigned)f2bf(s[4] * iz) | ((unsigned)f2bf(s[5] * iz) << 16);
  o.w = (unsigned)f2bf(s[6] * iz) | ((unsigned)f2bf(s[7] * iz) << 16);
  *(uint4*)&memTb[(long)b * bs + r] = o;
}

// Qfin [NP][512] f32 -> d_out[b][ch][HW] (first 512 channels)
__global__ void k_out_q(const float* __restrict__ Qfin, float* __restrict__ dout) {
  __shared__ float t[32][33];
  long b = blockIdx.z;
  int q0 = blockIdx.x * 32, ch0 = blockIdx.y * 32;
  int tx = threadIdx.x, ty = threadIdx.y;
#pragma unroll
  for (int i = 0; i < 32; i += 8)
    t[ty + i][tx] = Qfin[b * ((long)NP * 512) + (long)(q0 + ty + i) * 512 + ch0 + tx];
  __syncthreads();
#pragma unroll
  for (int i = 0; i < 32; i += 8) {
    int ch = ch0 + ty + i, q = q0 + tx;
    if (q < HW)
      dout[b * ((long)1024 * HW) + (long)ch * HW + q] = t[tx][ty + i];
  }
}

__global__ void k_copy_q0(const float4* __restrict__ src, float4* __restrict__ dst) {
  int idx = blockIdx.x * 256 + threadIdx.x;
  long b = blockIdx.z;
  const long n4 = (long)DO_ * HW / 4;  // 199680
  if (idx < n4)
    dst[b * ((long)1024 * HW / 4) + n4 + idx] = src[b * n4 + idx];
}

// ---------- host ----------
extern "C" void kernel_launch(void* const* d_in, const int* in_sizes, int n_in,
                              void* d_out, int out_size, void* d_ws, size_t ws_size,
                              hipStream_t stream) {
  const float* m_in  = (const float*)d_in[0];
  const float* m_out = (const float*)d_in[1];
  const float* q_in  = (const float*)d_in[2];
  const float* q_out = (const float*)d_in[3];
  const float* wr    = (const float*)d_in[4];
  const float* br    = (const float*)d_in[5];
  const float* wu    = (const float*)d_in[6];
  const float* bu    = (const float*)d_in[7];
  const float* wc    = (const float*)d_in[8];
  const float* bc    = (const float*)d_in[9];
  float* dout = (float*)d_out;

  // workspace layout (~209 MB)
  char* p = (char*)d_ws;
  size_t off = 0;
  auto alloc = [&](size_t bytes) { void* r = p + off; off += (bytes + 255) & ~(size_t)255; return r; };
  u16*   miT    = (u16*)alloc((size_t)NB * KP * DE * 2);        // [b][k][128]
  u16*   qiT    = (u16*)alloc((size_t)NB * NP * DE * 2);        // [b][q][128]
  u16*   Pt     = (u16*)alloc((size_t)NB * NP * KP * 2);        // [b][q][k]
  float* invZ   = (float*)alloc((size_t)NB * NP * 4);
  u16*   moutb  = (u16*)alloc((size_t)NB * DO_ * KP * 2);       // [b][o][k]
  u16*   memTb  = (u16*)alloc((size_t)NB * NP * DO_ * 2);       // [b][q][o]
  u16*   chru   = (u16*)alloc((size_t)NB * NP * 1024 * 2);      // [b][q][r|u]
  u16*   qT     = (u16*)alloc((size_t)NB * NP * 512 * 2);       // [b][q][512]
  float* Qfin   = (float*)alloc((size_t)NB * NP * 512 * 4);
  u16*   Ppart  = (u16*)alloc((size_t)NB * PVSPLIT * NP * DO_ * 2);
  u16*   Wfu    = (u16*)alloc((size_t)512 * 512 * 2);
  u16*   Wfr    = (u16*)alloc((size_t)512 * 512 * 2);
  u16*   Wfuh   = (u16*)alloc((size_t)512 * 512 * 2);
  u16*   Wfrh   = (u16*)alloc((size_t)512 * 512 * 2);
  u16*   Wfc    = (u16*)alloc((size_t)512 * 1024 * 2);
  float* Zp     = (float*)memTb;   // [NB][49][NP] f32 alias (dead before memTb)
  if (off > ws_size) return;  // workspace too small -> fail visibly

  // --- prep: frag-ordered weights ---
  k_wfrag<<<dim3(1024), 256, 0, stream>>>(wu, Wfu, 1024, 0);
  k_wfrag<<<dim3(1024), 256, 0, stream>>>(wr, Wfr, 1024, 0);
  k_wfrag<<<dim3(1024), 256, 0, stream>>>(wu, Wfuh, 1024, 512);
  k_wfrag<<<dim3(1024), 256, 0, stream>>>(wr, Wfrh, 1024, 512);
  k_wfrag<<<dim3(2048), 256, 0, stream>>>(wc, Wfc, 1024, 0);
  // --- prep: inputs ---
  k_cast_pad<<<dim3(25, 512, NB), 256, 0, stream>>>(
      m_out, moutb, THW, KP, (long)DO_ * THW, (long)DO_ * KP);
  k_transpose_cast<<<dim3(196, 4, NB), dim3(32, 8), 0, stream>>>(
      m_in, miT, DE, THW, KP, DE, (long)DE * THW, (long)KP * DE);
  k_transpose_cast<<<dim3(52, 4, NB), dim3(32, 8), 0, stream>>>(
      q_in, qiT, DE, HW, NP, DE, (long)DE * HW, (long)NP * DE);
  k_transpose_cast<<<dim3(52, 16, NB), dim3(32, 8), 0, stream>>>(
      q_out, qT, DO_, HW, NP, 512, (long)DO_ * HW, (long)NP * 512);

  // --- attention scores + row-sum partials ---
  gemm_scores<<<dim3(26, 49, NB), 256, 0, stream>>>(qiT, miT, Zp, Pt);
  k_invz<<<dim3(26), 256, 0, stream>>>(Zp, invZ);

  // --- mem: Ppart = Pt @ moutb^T (BN=512, split-K x7, XCD-pinned) ---
  gemm_pv<<<dim3(728), 256, 0, stream>>>(Pt, moutb, Ppart);
  k_reduce_mem<<<dim3(1664), 256, 0, stream>>>(Ppart, invZ, memTb);

  // --- fused chru + 5 GRU layers ---
  gru_fused<<<dim3(26, NB), 512, 0, stream>>>(
      qT, memTb, Wfu, Wfr, Wfuh, Wfrh, Wfc, br, bu, bc, chru, Qfin);

  // --- outputs ---
  k_out_q<<<dim3(49, 16, NB), dim3(32, 8), 0, stream>>>(Qfin, dout);
  k_copy_q0<<<dim3(780, 1, NB), 256, 0, stream>>>((const float4*)q_out, (float4*)dout);
}

// Round 7
// 680.730 us; speedup vs baseline: 1.1118x; 1.1118x over previous
//
#include <hip/hip_runtime.h>
#include <hip/hip_bf16.h>
#include <math.h>

typedef unsigned short u16;
typedef __attribute__((ext_vector_type(8))) short bf16x8;
typedef __attribute__((ext_vector_type(4))) float f32x4;

// ---------- helpers ----------
__device__ __forceinline__ u16 f2bf(float f) {
  union { float f; unsigned u; } x; x.f = f;
  unsigned r = x.u + 0x7fffu + ((x.u >> 16) & 1u);
  return (u16)(r >> 16);
}
__device__ __forceinline__ float bf2f(u16 h) {
  union { unsigned u; float f; } x; x.u = ((unsigned)h) << 16;
  return x.f;
}
__device__ __forceinline__ float sigmf(float x) {
  x = fminf(fmaxf(x, -30.f), 30.f);
  return 1.f / (1.f + __expf(-x));
}
__device__ __forceinline__ float tanh_fast(float x) {
  x = fminf(fmaxf(x, -15.f), 15.f);
  float t = __expf(2.f * x);
  return (t - 1.f) / (t + 1.f);
}

// counted vmcnt wait (T4): wait until <= N vector-mem ops outstanding
template<int N> __device__ __forceinline__ void wait_vmcnt() {
  if constexpr (N == 0)      asm volatile("s_waitcnt vmcnt(0)" ::: "memory");
  else if constexpr (N == 4) asm volatile("s_waitcnt vmcnt(4)" ::: "memory");
  else if constexpr (N == 6) asm volatile("s_waitcnt vmcnt(6)" ::: "memory");
  else if constexpr (N == 9) asm volatile("s_waitcnt vmcnt(9)" ::: "memory");
  else static_assert(N == 0 || N == 4 || N == 6 || N == 9, "add vmcnt case");
}

// ---------- problem constants ----------
#define NB 4
#define DE 128
#define DO_ 512
#define HW 1560
#define THW 6240
#define NP 1664   // HW padded to 13*128
#define KP 6272   // THW padded to 49*128
#define PROP 5
#define PVSPLIT 7
#define PVKC 896  // 6272/7 = 28*32

// ---------- generic bf16 GEMM core: C[M,N] = A[M,K] * Bt[N,K]^T ----------
// Tile BMT x 128, K-step BKT, 4 waves, 16x16x32 MFMA, global_load_lds
// double-buffer with COUNTED vmcnt + raw barriers (loads stay in flight
// across barriers; no vmcnt(0) drain in the main loop).
template<int MODE, int BMT, int BKT>
__device__ __forceinline__
void gemm_core(const u16* __restrict__ A, const u16* __restrict__ Bt,
               int K, int lda, int ldb, long a_bs, long b_bs,
               void* __restrict__ out0v, long o0_bs, int ld0,
               u16* __restrict__ out1, long o1_bs, int ld1,
               const void* __restrict__ e0v, long e0_bs,
               const void* __restrict__ e1v, long e1_bs,
               const void* __restrict__ e2v, long e2_bs,
               int nvalid, float scale)
{
  constexpr int WR = BMT / 64;        // wave rows (2 or 1)
  constexpr int WC = 4 / WR;          // wave cols (2 or 4)
  constexpr int NF = 8 / WC;          // 16-wide n-frags per wave
  constexpr int KK = BKT / 32;        // k-subtiles per step
  constexpr int ASLOT = BMT * BKT / 8;
  constexpr int BSLOT = 128 * BKT / 8;
  constexpr int NISS = (ASLOT + BSLOT) / 256;
  constexpr int RSH = (BMT == 128) ? 7 : 6;
  __shared__ u16 lds[2][ASLOT + BSLOT][8];

  const int tid = threadIdx.x;
  const int wave = tid >> 6, lane = tid & 63;
  const int kg = lane >> 4, lr = lane & 15;
  const int wrw = wave / WC, wcw = wave % WC;
  const long b = blockIdx.z;
  const int m0 = blockIdx.x * BMT, n0 = blockIdx.y * 128;
  A += b * a_bs; Bt += b * b_bs;

  float* out0f = (float*)out0v;
  u16* out0h = (u16*)out0v;
  const float* e0f = (const float*)e0v;
  const u16* e0h = (const u16*)e0v;
  const u16* e1h = (const u16*)e1v;
  const u16* e2h = (const u16*)e2v;

  auto stage = [&](int buf, int kt) {
#pragma unroll
    for (int i = 0; i < NISS; ++i) {
      int s = tid + 256 * i;
      const u16* src;
      if (s < ASLOT) {
        int row = s & (BMT - 1), g = s >> RSH;
        src = A + (long)(m0 + row) * lda + kt + g * 8;
      } else {
        int s2 = s - ASLOT;
        int row = s2 & 127, g = s2 >> 7;
        src = Bt + (long)(n0 + row) * ldb + kt + g * 8;
      }
      __builtin_amdgcn_global_load_lds(
          (const __attribute__((address_space(1))) void*)src,
          (__attribute__((address_space(3))) void*)&lds[buf][wave * 64 + 256 * i][0],
          16, 0, 0);
    }
  };

  f32x4 acc[4][NF];
#pragma unroll
  for (int m = 0; m < 4; ++m)
#pragma unroll
    for (int n = 0; n < NF; ++n) acc[m][n] = (f32x4){0.f, 0.f, 0.f, 0.f};

  const int nt = K / BKT;
  stage(0, 0);
  for (int t = 0; t < nt; ++t) {
    int cur = t & 1;
    if (t + 1 < nt) {
      stage(cur ^ 1, (t + 1) * BKT);   // issue next tile, then wait only for cur
      wait_vmcnt<NISS>();
    } else {
      wait_vmcnt<0>();
    }
    __builtin_amdgcn_s_barrier();      // cur tile visible to all waves
    bf16x8 af[KK][4], bfr[KK][NF];
#pragma unroll
    for (int kk = 0; kk < KK; ++kk) {
#pragma unroll
      for (int m = 0; m < 4; ++m)
        af[kk][m] = *(const bf16x8*)&lds[cur][(kk * 4 + kg) * BMT + wrw * 64 + m * 16 + lr][0];
#pragma unroll
      for (int n = 0; n < NF; ++n)
        bfr[kk][n] = *(const bf16x8*)&lds[cur][ASLOT + (kk * 4 + kg) * 128 + (wcw * NF + n) * 16 + lr][0];
    }
#pragma unroll
    for (int kk = 0; kk < KK; ++kk)
#pragma unroll
      for (int m = 0; m < 4; ++m)
#pragma unroll
        for (int n = 0; n < NF; ++n)
          acc[m][n] = __builtin_amdgcn_mfma_f32_16x16x32_bf16(af[kk][m], bfr[kk][n], acc[m][n], 0, 0, 0);
    __builtin_amdgcn_s_barrier();      // all waves done reading cur (safe to overwrite)
  }

  // frag elem j -> row = m0+wrw*64+m*16+kg*4+j, col = n0+(wcw*NF+n)*16+lr
  if constexpr (MODE == 0) {
    float rs[4][4];
#pragma unroll
    for (int m = 0; m < 4; ++m)
#pragma unroll
      for (int j = 0; j < 4; ++j) rs[m][j] = 0.f;
#pragma unroll
    for (int m = 0; m < 4; ++m) {
      int rloc = wrw * 64 + m * 16 + kg * 4;
#pragma unroll
      for (int n = 0; n < NF; ++n) {
        int col = n0 + (wcw * NF + n) * 16 + lr;
#pragma unroll
        for (int j = 0; j < 4; ++j) {
          long row = m0 + rloc + j;
          float p = __expf(acc[m][n][j] * scale);
          bool valid = (col < nvalid);
          out1[b * o1_bs + row * ld1 + col] = valid ? f2bf(p) : (u16)0;
          rs[m][j] += valid ? p : 0.f;
        }
      }
    }
#pragma unroll
    for (int m = 0; m < 4; ++m)
#pragma unroll
      for (int j = 0; j < 4; ++j) {
#pragma unroll
        for (int msk = 1; msk < 16; msk <<= 1)
          rs[m][j] += __shfl_xor(rs[m][j], msk, 64);
      }
    float* zbuf = (float*)lds;  // 2*128 floats
    if (lr == 0) {
#pragma unroll
      for (int m = 0; m < 4; ++m)
#pragma unroll
        for (int j = 0; j < 4; ++j)
          zbuf[wcw * 128 + wrw * 64 + m * 16 + kg * 4 + j] = rs[m][j];
    }
    __syncthreads();
    if (tid < 128)
      out0f[b * o0_bs + (long)blockIdx.y * NP + (m0 + tid)] = zbuf[tid] + zbuf[128 + tid];
    return;
  }

#pragma unroll
  for (int m = 0; m < 4; ++m) {
    int rloc = wrw * 64 + m * 16 + kg * 4;
#pragma unroll
    for (int n = 0; n < NF; ++n) {
      int col = n0 + (wcw * NF + n) * 16 + lr;
#pragma unroll
      for (int j = 0; j < 4; ++j) {
        long row = m0 + rloc + j;
        float v = acc[m][n][j];
        if constexpr (MODE == 2) {        // Chru(bf16) = memT @ Wruh^T + bias_ru
          out1[b * o1_bs + row * ld1 + col] = f2bf(v + e0f[col]);
        } else if constexpr (MODE == 3) { // gates r,u (chru bf16, mem bf16)
          float gt = sigmf(v + bf2f(e0h[b * e0_bs + row * 1024 + col]));
          if (col < 512)                  // r -> RH = r*mem into XR cols 512..1023
            out1[b * o1_bs + row * ld1 + 512 + col] =
                f2bf(gt * bf2f(e1h[b * e1_bs + row * 512 + col]));
          else                            // u -> U (bf16)
            out0h[b * o0_bs + row * ld0 + (col - 512)] = f2bf(gt);
        } else if constexpr (MODE == 4) { // candidate + GRU update
          float cg = tanh_fast(v + e0f[col]);
          float u = bf2f(e1h[b * e1_bs + row * 512 + col]);
          float mm = bf2f(e2h[b * e2_bs + row * 512 + col]);
          float x = mm * (1.f - u) + u * cg;
          out1[b * o1_bs + row * ld1 + col] = f2bf(x);
          if (out0f) out0f[b * o0_bs + row * ld0 + col] = x;
        }
      }
    }
  }
}

#define GEMM_ARGS                                                              \
  const u16* __restrict__ A, const u16* __restrict__ Bt, int K, int lda,       \
  int ldb, long a_bs, long b_bs, void* __restrict__ out0v, long o0_bs,         \
  int ld0, u16* __restrict__ out1, long o1_bs, int ld1,                        \
  const void* __restrict__ e0v, long e0_bs, const void* __restrict__ e1v,      \
  long e1_bs, const void* __restrict__ e2v, long e2_bs, int nvalid, float scale
#define GEMM_PASS A, Bt, K, lda, ldb, a_bs, b_bs, out0v, o0_bs, ld0, out1,     \
  o1_bs, ld1, e0v, e0_bs, e1v, e1_bs, e2v, e2_bs, nvalid, scale

__global__ __launch_bounds__(256) void gk_scores(GEMM_ARGS) { gemm_core<0, 128, 32>(GEMM_PASS); }
__global__ __launch_bounds__(256) void gk_chru(GEMM_ARGS)   { gemm_core<2, 64, 64>(GEMM_PASS); }
__global__ __launch_bounds__(256) void gk_gates(GEMM_ARGS)  { gemm_core<3, 64, 64>(GEMM_PASS); }
__global__ __launch_bounds__(256) void gk_cand(GEMM_ARGS)   { gemm_core<4, 64, 64>(GEMM_PASS); }

// ========== mem GEMM: Ppart[b,z] = Pt(k-chunk z) @ moutb^T, BN=512 =========
// 728 blocks, XCD-pinned decode (consecutive m-blocks of one (b,z) pair land
// on one XCD -> B-slice L2-resident). A LDS-dbuf, B reg-prefetch, counted
// vmcnt (8 B-loads + 1 stage in flight across barriers).
__global__ __launch_bounds__(256)
void gemm_pv(const u16* __restrict__ Pt, const u16* __restrict__ moutb,
             u16* __restrict__ Ppart)
{
  const int bid = blockIdx.x;            // 0..727
  const int xcd = bid & 7, i = bid >> 3; // i 0..90
  const int s = xcd * 91 + i;            // 0..727
  const int pair = s / 26, mb = s - pair * 26;
  const int b = pair / PVSPLIT, z = pair - b * PVSPLIT;
  const int m0 = mb * 64;
  const int k0 = z * PVKC;               // 28 steps of 32

  const u16* A = Pt + (long)b * NP * KP;
  const u16* B0;
  {
    const u16* Bb = moutb + (long)b * DO_ * KP;
    B0 = Bb + (long)((threadIdx.x >> 6) * 128 + (threadIdx.x & 15)) * KP +
         ((threadIdx.x & 63) >> 4) * 8;
  }

  __shared__ u16 lds[2][2048];
  const int tid = threadIdx.x;
  const int wave = tid >> 6, lane = tid & 63;
  const int kg = lane >> 4, lr = lane & 15;

  auto stage = [&](int buf, int kt) {
    int row = tid & 63, g = tid >> 6;
    const u16* src = A + (long)(m0 + row) * KP + kt + g * 8;
    __builtin_amdgcn_global_load_lds(
        (const __attribute__((address_space(1))) void*)src,
        (__attribute__((address_space(3))) void*)&lds[buf][(wave * 64) * 8],
        16, 0, 0);
  };

  f32x4 acc[4][8];
#pragma unroll
  for (int m = 0; m < 4; ++m)
#pragma unroll
    for (int n = 0; n < 8; ++n) acc[m][n] = (f32x4){0.f, 0.f, 0.f, 0.f};

  bf16x8 bra[8], brb[8];
#pragma unroll
  for (int n = 0; n < 8; ++n)
    bra[n] = *(const bf16x8*)&B0[(long)n * 16 * KP + k0];
  stage(0, k0);

#define PV_STEP(BU, BL, T, CUR)                                                  \
  {                                                                              \
    if ((T) + 1 < 28) {                                                          \
      int ktn = k0 + ((T) + 1) * 32;                                             \
      _Pragma("unroll") for (int n = 0; n < 8; ++n)                              \
          BL[n] = *(const bf16x8*)&B0[(long)n * 16 * KP + ktn];                  \
      stage((CUR) ^ 1, ktn);                                                     \
      wait_vmcnt<9>();                                                           \
    } else {                                                                     \
      wait_vmcnt<0>();                                                           \
    }                                                                            \
    __builtin_amdgcn_s_barrier();                                                \
    bf16x8 af[4];                                                                \
    _Pragma("unroll") for (int m = 0; m < 4; ++m)                                \
        af[m] = *(const bf16x8*)&lds[CUR][(kg * 64 + m * 16 + lr) * 8];          \
    _Pragma("unroll") for (int m = 0; m < 4; ++m)                                \
        _Pragma("unroll") for (int n = 0; n < 8; ++n)                            \
            acc[m][n] = __builtin_amdgcn_mfma_f32_16x16x32_bf16(af[m], BU[n],    \
                                                                acc[m][n], 0, 0, 0); \
    __builtin_amdgcn_s_barrier();                                                \
  }

  for (int tp = 0; tp < 14; ++tp) {
    PV_STEP(bra, brb, 2 * tp, 0);
    PV_STEP(brb, bra, 2 * tp + 1, 1);
  }
#undef PV_STEP

  u16* out = Ppart + (long)(b * PVSPLIT + z) * NP * DO_;
#pragma unroll
  for (int m = 0; m < 4; ++m) {
#pragma unroll
    for (int n = 0; n < 8; ++n) {
      int col = wave * 128 + n * 16 + lr;
#pragma unroll
      for (int j = 0; j < 4; ++j) {
        int row = m0 + m * 16 + kg * 4 + j;
        out[(long)row * DO_ + col] = f2bf(acc[m][n][j]);
      }
    }
  }
}

// ---------- small kernels ----------
__global__ void k_transpose_cast(const float* __restrict__ in, u16* __restrict__ out,
                                 int R, int C, int Cp, int out_ld,
                                 long in_bs, long out_bs) {
  __shared__ float t[32][33];
  long b = blockIdx.z;
  int c0 = blockIdx.x * 32, r0 = blockIdx.y * 32;
  int tx = threadIdx.x, ty = threadIdx.y;
#pragma unroll
  for (int i = 0; i < 32; i += 8) {
    int r = r0 + ty + i, c = c0 + tx;
    t[ty + i][tx] = (r < R && c < C) ? in[b * in_bs + (long)r * C + c] : 0.f;
  }
  __syncthreads();
#pragma unroll
  for (int i = 0; i < 32; i += 8) {
    int c = c0 + ty + i, r = r0 + tx;
    if (c < Cp && r < R)
      out[b * out_bs + (long)c * out_ld + r] = f2bf(t[tx][ty + i]);
  }
}

__global__ void k_cast_pad(const float* __restrict__ in, u16* __restrict__ out,
                           int Cin, int Cout, long in_bs, long out_bs) {
  int c = blockIdx.x * 256 + threadIdx.x;
  int r = blockIdx.y;
  long b = blockIdx.z;
  if (c >= Cout) return;
  out[b * out_bs + (long)r * Cout + c] =
      (c < Cin) ? f2bf(in[b * in_bs + (long)r * Cin + c]) : (u16)0;
}

__global__ void k_build_wru(const float* __restrict__ wr_, const float* __restrict__ wu_,
                            u16* __restrict__ wrux, u16* __restrict__ wruh) {
  int k = blockIdx.x * 256 + threadIdx.x;  // 0..511
  int m = blockIdx.y;                      // 0..1023
  if (k >= 512) return;
  const float* src = (m < 512) ? wr_ : wu_;
  int mm = m & 511;
  wrux[m * 512 + k] = f2bf(src[mm * 1024 + k]);
  wruh[m * 512 + k] = f2bf(src[mm * 1024 + 512 + k]);
}

__global__ void k_bias_ru(const float* __restrict__ br_, const float* __restrict__ bu_,
                          float* __restrict__ bias) {
  int i = blockIdx.x * 256 + threadIdx.x;
  if (i < 1024) bias[i] = (i < 512) ? br_[i] : bu_[i - 512];
}

__global__ void k_invz(const float* __restrict__ Zp, float* __restrict__ invZ) {
  int t = blockIdx.x * 256 + threadIdx.x;
  if (t >= NB * NP) return;
  int b = t / NP, q = t - b * NP;
  const float* base = Zp + (long)b * 49 * NP + q;
  float s = 0.f;
#pragma unroll
  for (int nb = 0; nb < 49; ++nb) s += base[(long)nb * NP];
  invZ[t] = 1.f / s;
}

__global__ void k_reduce_mem(const u16* __restrict__ Ppart, const float* __restrict__ invZ,
                             u16* __restrict__ memTb) {
  long t = (long)blockIdx.x * 256 + threadIdx.x;   // uint4 index (8 bf16)
  const long bs = (long)NP * DO_;
  if (t >= (long)NB * bs / 8) return;
  long flat = t * 8;
  int b = (int)(flat / bs);
  long r = flat - (long)b * bs;
  int q = (int)(r / DO_);
  float s[8];
#pragma unroll
  for (int e = 0; e < 8; ++e) s[e] = 0.f;
#pragma unroll
  for (int z = 0; z < PVSPLIT; ++z) {
    uint4 v = *(const uint4*)&Ppart[(long)(b * PVSPLIT + z) * bs + r];
    s[0] += bf2f((u16)(v.x & 0xffff)); s[1] += bf2f((u16)(v.x >> 16));
    s[2] += bf2f((u16)(v.y & 0xffff)); s[3] += bf2f((u16)(v.y >> 16));
    s[4] += bf2f((u16)(v.z & 0xffff)); s[5] += bf2f((u16)(v.z >> 16));
    s[6] += bf2f((u16)(v.w & 0xffff)); s[7] += bf2f((u16)(v.w >> 16));
  }
  float iz = invZ[b * NP + q];
  uint4 o;
  o.x = (unsigned)f2bf(s[0] * iz) | ((unsigned)f2bf(s[1] * iz) << 16);
  o.y = (unsigned)f2bf(s[2] * iz) | ((unsigned)f2bf(s[3] * iz) << 16);
  o.z = (unsigned)f2bf(s[4] * iz) | ((unsigned)f2bf(s[5] * iz) << 16);
  o.w = (unsigned)f2bf(s[6] * iz) | ((unsigned)f2bf(s[7] * iz) << 16);
  *(uint4*)&memTb[(long)b * bs + r] = o;
}

__global__ void k_out_q(const float* __restrict__ Qfin, float* __restrict__ dout) {
  __shared__ float t[32][33];
  long b = blockIdx.z;
  int q0 = blockIdx.x * 32, ch0 = blockIdx.y * 32;
  int tx = threadIdx.x, ty = threadIdx.y;
#pragma unroll
  for (int i = 0; i < 32; i += 8)
    t[ty + i][tx] = Qfin[b * ((long)NP * 512) + (long)(q0 + ty + i) * 512 + ch0 + tx];
  __syncthreads();
#pragma unroll
  for (int i = 0; i < 32; i += 8) {
    int ch = ch0 + ty + i, q = q0 + tx;
    if (q < HW)
      dout[b * ((long)1024 * HW) + (long)ch * HW + q] = t[tx][ty + i];
  }
}

__global__ void k_copy_q0(const float4* __restrict__ src, float4* __restrict__ dst) {
  int idx = blockIdx.x * 256 + threadIdx.x;
  long b = blockIdx.z;
  const long n4 = (long)DO_ * HW / 4;  // 199680
  if (idx < n4)
    dst[b * ((long)1024 * HW / 4) + n4 + idx] = src[b * n4 + idx];
}

// ---------- host ----------
extern "C" void kernel_launch(void* const* d_in, const int* in_sizes, int n_in,
                              void* d_out, int out_size, void* d_ws, size_t ws_size,
                              hipStream_t stream) {
  const float* m_in  = (const float*)d_in[0];
  const float* m_out = (const float*)d_in[1];
  const float* q_in  = (const float*)d_in[2];
  const float* q_out = (const float*)d_in[3];
  const float* wr    = (const float*)d_in[4];
  const float* br    = (const float*)d_in[5];
  const float* wu    = (const float*)d_in[6];
  const float* bu    = (const float*)d_in[7];
  const float* wc    = (const float*)d_in[8];
  const float* bc    = (const float*)d_in[9];
  float* dout = (float*)d_out;

  // workspace layout (all sizes 256B-multiples)
  char* p = (char*)d_ws;
  size_t off = 0;
  auto alloc = [&](size_t bytes) { void* r = p + off; off += (bytes + 255) & ~(size_t)255; return r; };
  u16*   miT    = (u16*)alloc((size_t)NB * KP * DE * 2);       // [b][k][128]
  u16*   qiT    = (u16*)alloc((size_t)NB * NP * DE * 2);       // [b][q][128]
  u16*   Pt     = (u16*)alloc((size_t)NB * NP * KP * 2);       // [b][q][k]
  float* invZ   = (float*)alloc((size_t)NB * NP * 4);
  u16*   moutb  = (u16*)alloc((size_t)NB * DO_ * KP * 2);      // [b][o][k]
  u16*   memTb  = (u16*)alloc((size_t)NB * NP * DO_ * 2);      // [b][q][o]
  // chru,U,XRb,Qfin contiguous: pv partials (28 * NP*DO_*2 = 47.7MB) alias
  // this exact 47.7MB span (all four dead until after k_reduce_mem).
  u16*   chru   = (u16*)alloc((size_t)NB * NP * 1024 * 2);     // [b][q][r|u]
  u16*   U      = (u16*)alloc((size_t)NB * NP * DO_ * 2);
  u16*   XRb    = (u16*)alloc((size_t)NB * NP * 1024 * 2);
  float* Qfin   = (float*)alloc((size_t)NB * NP * DO_ * 4);
  u16*   XRa    = (u16*)alloc((size_t)NB * NP * 1024 * 2);     // [b][q][x|rh]
  u16*   wrux   = (u16*)alloc((size_t)1024 * 512 * 2);
  u16*   wruh   = (u16*)alloc((size_t)1024 * 512 * 2);
  u16*   wcb    = (u16*)alloc((size_t)512 * 1024 * 2);
  float* biasru = (float*)alloc((size_t)1024 * 4);
  u16*   Ppart  = (u16*)chru;      // [NB*PVSPLIT][NP][DO_] bf16, alias
  float* Zp     = (float*)memTb;   // [NB][49][NP] f32, alias (dead before memTb)
  if (off > ws_size) return;

  // --- prep: weights ---
  k_build_wru<<<dim3(2, 1024), 256, 0, stream>>>(wr, wu, wrux, wruh);
  k_cast_pad<<<dim3(4, 512, 1), 256, 0, stream>>>(wc, wcb, 1024, 1024, 0, 0);
  k_bias_ru<<<dim3(4), 256, 0, stream>>>(br, bu, biasru);
  // --- prep: inputs ---
  k_cast_pad<<<dim3(25, 512, NB), 256, 0, stream>>>(
      m_out, moutb, THW, KP, (long)DO_ * THW, (long)DO_ * KP);
  k_transpose_cast<<<dim3(196, 4, NB), dim3(32, 8), 0, stream>>>(
      m_in, miT, DE, THW, KP, DE, (long)DE * THW, (long)KP * DE);
  k_transpose_cast<<<dim3(52, 4, NB), dim3(32, 8), 0, stream>>>(
      q_in, qiT, DE, HW, NP, DE, (long)DE * HW, (long)NP * DE);
  k_transpose_cast<<<dim3(52, 16, NB), dim3(32, 8), 0, stream>>>(
      q_out, XRa, DO_, HW, NP, 1024, (long)DO_ * HW, (long)NP * 1024);

  // --- attention scores: Pt = exp(S/sqrt(De)); Zp row-sum partials ---
  gk_scores<<<dim3(13, 49, NB), 256, 0, stream>>>(
      qiT, miT, DE, DE, DE, (long)NP * DE, (long)KP * DE,
      Zp, (long)49 * NP, 0, Pt, (long)NP * KP, KP,
      nullptr, 0, nullptr, 0, nullptr, 0, THW, 0.08838834764831845f);
  k_invz<<<dim3(26), 256, 0, stream>>>(Zp, invZ);

  // --- mem: Ppart = Pt @ moutb^T (BN=512, split-K x7, XCD-pinned) ---
  gemm_pv<<<dim3(728), 256, 0, stream>>>(Pt, moutb, Ppart);
  k_reduce_mem<<<dim3(1664), 256, 0, stream>>>(Ppart, invZ, memTb);

  // --- Chru(bf16) = memT @ Wruh^T + [br;bu] ---
  gk_chru<<<dim3(26, 8, NB), 256, 0, stream>>>(
      memTb, wruh, DO_, DO_, DO_, (long)NP * DO_, 0,
      nullptr, 0, 0, chru, (long)NP * 1024, 1024,
      biasru, 0, nullptr, 0, nullptr, 0, 0, 0.f);

  // --- GRU layers ---
  u16* xr[2] = {XRa, XRb};
  for (int l = 0; l < PROP; ++l) {
    u16* cur = xr[l & 1];
    u16* nxt = xr[(l + 1) & 1];
    gk_gates<<<dim3(26, 8, NB), 256, 0, stream>>>(
        cur, wrux, DO_, 1024, DO_, (long)NP * 1024, 0,
        U, (long)NP * DO_, DO_, cur, (long)NP * 1024, 1024,
        chru, (long)NP * 1024, memTb, (long)NP * DO_, nullptr, 0, 0, 0.f);
    gk_cand<<<dim3(26, 4, NB), 256, 0, stream>>>(
        cur, wcb, 1024, 1024, 1024, (long)NP * 1024, 0,
        (l == PROP - 1) ? (void*)Qfin : nullptr, (long)NP * DO_, DO_,
        nxt, (long)NP * 1024, 1024,
        bc, 0, U, (long)NP * DO_, memTb, (long)NP * DO_, 0, 0.f);
  }

  // --- outputs ---
  k_out_q<<<dim3(49, 16, NB), dim3(32, 8), 0, stream>>>(Qfin, dout);
  k_copy_q0<<<dim3(780, 1, NB), 256, 0, stream>>>((const float4*)q_out, (float4*)dout);
}

// Round 8
// 656.723 us; speedup vs baseline: 1.1525x; 1.0366x over previous
//
#include <hip/hip_runtime.h>
#include <hip/hip_bf16.h>
#include <math.h>

typedef unsigned short u16;
typedef __attribute__((ext_vector_type(8))) short bf16x8;
typedef __attribute__((ext_vector_type(4))) float f32x4;

// ---------- helpers ----------
__device__ __forceinline__ u16 f2bf(float f) {
  union { float f; unsigned u; } x; x.f = f;
  unsigned r = x.u + 0x7fffu + ((x.u >> 16) & 1u);
  return (u16)(r >> 16);
}
__device__ __forceinline__ float bf2f(u16 h) {
  union { unsigned u; float f; } x; x.u = ((unsigned)h) << 16;
  return x.f;
}
__device__ __forceinline__ float sigmf(float x) {
  x = fminf(fmaxf(x, -30.f), 30.f);
  return 1.f / (1.f + __expf(-x));
}
__device__ __forceinline__ float tanh_fast(float x) {
  x = fminf(fmaxf(x, -15.f), 15.f);
  float t = __expf(2.f * x);
  return (t - 1.f) / (t + 1.f);
}

// counted vmcnt wait (T4)
template<int N> __device__ __forceinline__ void wait_vmcnt() {
  if constexpr (N == 0)      asm volatile("s_waitcnt vmcnt(0)" ::: "memory");
  else if constexpr (N == 4) asm volatile("s_waitcnt vmcnt(4)" ::: "memory");
  else if constexpr (N == 6) asm volatile("s_waitcnt vmcnt(6)" ::: "memory");
  else static_assert(N == 0 || N == 4 || N == 6, "add vmcnt case");
}

// ---------- problem constants ----------
#define NB 4
#define DE 128
#define DO_ 512
#define HW 1560
#define THW 6240
#define NP 1664   // HW padded to 13*128
#define KP 6272   // THW padded to 49*128
#define PROP 5
#define PVSPLIT 7
#define PVKC 896  // 6272/7 = 28*32

// ---------- generic bf16 GEMM core: C[M,N] = A[M,K] * Bt[N,K]^T ----------
// Tile BMT x 128, K-step BKT, 4 waves, 16x16x32 MFMA, global_load_lds
// double-buffer, counted vmcnt + raw barriers (chain kernels).
template<int MODE, int BMT, int BKT>
__device__ __forceinline__
void gemm_core(const u16* __restrict__ A, const u16* __restrict__ Bt,
               int K, int lda, int ldb, long a_bs, long b_bs,
               void* __restrict__ out0v, long o0_bs, int ld0,
               u16* __restrict__ out1, long o1_bs, int ld1,
               u16* __restrict__ out2, long o2_bs,
               const void* __restrict__ e0v, long e0_bs,
               const void* __restrict__ e1v, long e1_bs,
               const void* __restrict__ e2v, long e2_bs,
               const void* __restrict__ e3v, long e3_bs,
               int nvalid, float scale)
{
  constexpr int WR = BMT / 64;        // wave rows (2 or 1)
  constexpr int WC = 4 / WR;          // wave cols (2 or 4)
  constexpr int NF = 8 / WC;          // 16-wide n-frags per wave
  constexpr int KK = BKT / 32;        // k-subtiles per step
  constexpr int ASLOT = BMT * BKT / 8;
  constexpr int BSLOT = 128 * BKT / 8;
  constexpr int NISS = (ASLOT + BSLOT) / 256;
  constexpr int RSH = (BMT == 128) ? 7 : 6;
  __shared__ u16 lds[2][ASLOT + BSLOT][8];

  const int tid = threadIdx.x;
  const int wave = tid >> 6, lane = tid & 63;
  const int kg = lane >> 4, lr = lane & 15;
  const int wrw = wave / WC, wcw = wave % WC;
  const long b = blockIdx.z;
  const int m0 = blockIdx.x * BMT, n0 = blockIdx.y * 128;
  A += b * a_bs; Bt += b * b_bs;

  float* out0f = (float*)out0v;
  u16* out0h = (u16*)out0v;
  const float* e0f = (const float*)e0v;
  const u16* e0h = (const u16*)e0v;
  const u16* e1h = (const u16*)e1v;
  const u16* e2h = (const u16*)e2v;
  const u16* e3h = (const u16*)e3v;

  auto stage = [&](int buf, int kt) {
#pragma unroll
    for (int i = 0; i < NISS; ++i) {
      int s = tid + 256 * i;
      const u16* src;
      if (s < ASLOT) {
        int row = s & (BMT - 1), g = s >> RSH;
        src = A + (long)(m0 + row) * lda + kt + g * 8;
      } else {
        int s2 = s - ASLOT;
        int row = s2 & 127, g = s2 >> 7;
        src = Bt + (long)(n0 + row) * ldb + kt + g * 8;
      }
      __builtin_amdgcn_global_load_lds(
          (const __attribute__((address_space(1))) void*)src,
          (__attribute__((address_space(3))) void*)&lds[buf][wave * 64 + 256 * i][0],
          16, 0, 0);
    }
  };

  f32x4 acc[4][NF];
#pragma unroll
  for (int m = 0; m < 4; ++m)
#pragma unroll
    for (int n = 0; n < NF; ++n) acc[m][n] = (f32x4){0.f, 0.f, 0.f, 0.f};

  const int nt = K / BKT;
  stage(0, 0);
  for (int t = 0; t < nt; ++t) {
    int cur = t & 1;
    if (t + 1 < nt) {
      stage(cur ^ 1, (t + 1) * BKT);   // next tile stays in flight across barrier
      wait_vmcnt<NISS>();
    } else {
      wait_vmcnt<0>();
    }
    __builtin_amdgcn_s_barrier();
    bf16x8 af[KK][4], bfr[KK][NF];
#pragma unroll
    for (int kk = 0; kk < KK; ++kk) {
#pragma unroll
      for (int m = 0; m < 4; ++m)
        af[kk][m] = *(const bf16x8*)&lds[cur][(kk * 4 + kg) * BMT + wrw * 64 + m * 16 + lr][0];
#pragma unroll
      for (int n = 0; n < NF; ++n)
        bfr[kk][n] = *(const bf16x8*)&lds[cur][ASLOT + (kk * 4 + kg) * 128 + (wcw * NF + n) * 16 + lr][0];
    }
#pragma unroll
    for (int kk = 0; kk < KK; ++kk)
#pragma unroll
      for (int m = 0; m < 4; ++m)
#pragma unroll
        for (int n = 0; n < NF; ++n)
          acc[m][n] = __builtin_amdgcn_mfma_f32_16x16x32_bf16(af[kk][m], bfr[kk][n], acc[m][n], 0, 0, 0);
    __builtin_amdgcn_s_barrier();
  }

  // frag elem j -> row = m0+wrw*64+m*16+kg*4+j, col = n0+(wcw*NF+n)*16+lr
  if constexpr (MODE == 0) {
    float rs[4][4];
#pragma unroll
    for (int m = 0; m < 4; ++m)
#pragma unroll
      for (int j = 0; j < 4; ++j) rs[m][j] = 0.f;
#pragma unroll
    for (int m = 0; m < 4; ++m) {
      int rloc = wrw * 64 + m * 16 + kg * 4;
#pragma unroll
      for (int n = 0; n < NF; ++n) {
        int col = n0 + (wcw * NF + n) * 16 + lr;
#pragma unroll
        for (int j = 0; j < 4; ++j) {
          long row = m0 + rloc + j;
          float p = __expf(acc[m][n][j] * scale);
          bool valid = (col < nvalid);
          out1[b * o1_bs + row * ld1 + col] = valid ? f2bf(p) : (u16)0;
          rs[m][j] += valid ? p : 0.f;
        }
      }
    }
#pragma unroll
    for (int m = 0; m < 4; ++m)
#pragma unroll
      for (int j = 0; j < 4; ++j) {
#pragma unroll
        for (int msk = 1; msk < 16; msk <<= 1)
          rs[m][j] += __shfl_xor(rs[m][j], msk, 64);
      }
    float* zbuf = (float*)lds;  // 2*128 floats
    if (lr == 0) {
#pragma unroll
      for (int m = 0; m < 4; ++m)
#pragma unroll
        for (int j = 0; j < 4; ++j)
          zbuf[wcw * 128 + wrw * 64 + m * 16 + kg * 4 + j] = rs[m][j];
    }
    __syncthreads();
    if (tid < 128)
      out0f[b * o0_bs + (long)blockIdx.y * NP + (m0 + tid)] = zbuf[tid] + zbuf[128 + tid];
    return;
  }

#pragma unroll
  for (int m = 0; m < 4; ++m) {
    int rloc = wrw * 64 + m * 16 + kg * 4;
#pragma unroll
    for (int n = 0; n < NF; ++n) {
      int col = n0 + (wcw * NF + n) * 16 + lr;
#pragma unroll
      for (int j = 0; j < 4; ++j) {
        long row = m0 + rloc + j;
        float v = acc[m][n][j];
        if constexpr (MODE == 2) {        // Chru(bf16) = memT @ Wruh^T + bias_ru
          out1[b * o1_bs + row * ld1 + col] = f2bf(v + e0f[col]);
        } else if constexpr (MODE == 3) { // gates r,u + cand-X partial
          if (col < 1024) {
            float gt = sigmf(v + bf2f(e0h[b * e0_bs + row * 1024 + col]));
            if (col < 512)                // r -> RH = r*mem into XR cols 512..1023
              out1[b * o1_bs + row * ld1 + 512 + col] =
                  f2bf(gt * bf2f(e1h[b * e1_bs + row * 512 + col]));
            else                          // u -> U (bf16)
              out0h[b * o0_bs + row * ld0 + (col - 512)] = f2bf(gt);
          } else {                        // Cx = X @ Wc_x (raw logit partial)
            out2[b * o2_bs + row * 512 + (col - 1024)] = f2bf(v);
          }
        } else if constexpr (MODE == 4) { // candidate (RH half) + GRU update
          float cg = tanh_fast(v + bf2f(e3h[b * e3_bs + row * 512 + col]) + e0f[col]);
          float u = bf2f(e1h[b * e1_bs + row * 512 + col]);
          float mm = bf2f(e2h[b * e2_bs + row * 512 + col]);
          float x = mm * (1.f - u) + u * cg;
          out1[b * o1_bs + row * ld1 + col] = f2bf(x);
          if (out0f) out0f[b * o0_bs + row * ld0 + col] = x;
        }
      }
    }
  }
}

#define GEMM_ARGS                                                              \
  const u16* __restrict__ A, const u16* __restrict__ Bt, int K, int lda,       \
  int ldb, long a_bs, long b_bs, void* __restrict__ out0v, long o0_bs,         \
  int ld0, u16* __restrict__ out1, long o1_bs, int ld1,                        \
  u16* __restrict__ out2, long o2_bs,                                          \
  const void* __restrict__ e0v, long e0_bs, const void* __restrict__ e1v,      \
  long e1_bs, const void* __restrict__ e2v, long e2_bs,                        \
  const void* __restrict__ e3v, long e3_bs, int nvalid, float scale
#define GEMM_PASS A, Bt, K, lda, ldb, a_bs, b_bs, out0v, o0_bs, ld0, out1,     \
  o1_bs, ld1, out2, o2_bs, e0v, e0_bs, e1v, e1_bs, e2v, e2_bs, e3v, e3_bs,     \
  nvalid, scale

__global__ __launch_bounds__(256) void gk_scores(GEMM_ARGS) { gemm_core<0, 128, 32>(GEMM_PASS); }
__global__ __launch_bounds__(256) void gk_chru(GEMM_ARGS)   { gemm_core<2, 64, 64>(GEMM_PASS); }
__global__ __launch_bounds__(256) void gk_gates(GEMM_ARGS)  { gemm_core<3, 64, 64>(GEMM_PASS); }
__global__ __launch_bounds__(256) void gk_cand(GEMM_ARGS)   { gemm_core<4, 64, 64>(GEMM_PASS); }

// ========== mem GEMM: Ppart[b,z] = Pt(k-chunk z) @ moutb^T, BN=512 =========
// Round-5 proven structure (drain __syncthreads, reg-prefetch B, bounds(256,2))
// + XCD-pinned decode (26 m-blocks of one (b,z) share an XCD's L2).
__global__ __launch_bounds__(256, 2)
void gemm_pv(const u16* __restrict__ Pt, const u16* __restrict__ moutb,
             u16* __restrict__ Ppart)
{
  const int bid = blockIdx.x;            // 0..727
  const int xcd = bid & 7, i = bid >> 3; // i 0..90
  const int s = xcd * 91 + i;            // 0..727
  const int pair = s / 26, mb = s - pair * 26;
  const int b = pair / PVSPLIT, z = pair - b * PVSPLIT;
  const int m0 = mb * 64;
  const int k0 = z * PVKC;               // 28 steps of 32

  const u16* A = Pt + (long)b * NP * KP;
  const u16* B0;
  {
    const u16* Bb = moutb + (long)b * DO_ * KP;
    B0 = Bb + (long)((threadIdx.x >> 6) * 128 + (threadIdx.x & 15)) * KP +
         ((threadIdx.x & 63) >> 4) * 8;
  }

  __shared__ u16 lds[2][2048];
  const int tid = threadIdx.x;
  const int wave = tid >> 6, lane = tid & 63;
  const int kg = lane >> 4, lr = lane & 15;

  auto stage = [&](int buf, int kt) {
    int row = tid & 63, g = tid >> 6;
    const u16* src = A + (long)(m0 + row) * KP + kt + g * 8;
    __builtin_amdgcn_global_load_lds(
        (const __attribute__((address_space(1))) void*)src,
        (__attribute__((address_space(3))) void*)&lds[buf][(wave * 64) * 8],
        16, 0, 0);
  };

  f32x4 acc[4][8];
#pragma unroll
  for (int m = 0; m < 4; ++m)
#pragma unroll
    for (int n = 0; n < 8; ++n) acc[m][n] = (f32x4){0.f, 0.f, 0.f, 0.f};

  bf16x8 bra[8], brb[8];
#pragma unroll
  for (int n = 0; n < 8; ++n)
    bra[n] = *(const bf16x8*)&B0[(long)n * 16 * KP + k0];
  stage(0, k0);
  __syncthreads();

#define PV_STEP(BU, BL, T, CUR)                                                  \
  {                                                                              \
    if ((T) + 1 < 28) {                                                          \
      int ktn = k0 + ((T) + 1) * 32;                                             \
      _Pragma("unroll") for (int n = 0; n < 8; ++n)                              \
          BL[n] = *(const bf16x8*)&B0[(long)n * 16 * KP + ktn];                  \
      stage((CUR) ^ 1, ktn);                                                     \
    }                                                                            \
    bf16x8 af[4];                                                                \
    _Pragma("unroll") for (int m = 0; m < 4; ++m)                                \
        af[m] = *(const bf16x8*)&lds[CUR][(kg * 64 + m * 16 + lr) * 8];          \
    _Pragma("unroll") for (int m = 0; m < 4; ++m)                                \
        _Pragma("unroll") for (int n = 0; n < 8; ++n)                            \
            acc[m][n] = __builtin_amdgcn_mfma_f32_16x16x32_bf16(af[m], BU[n],    \
                                                                acc[m][n], 0, 0, 0); \
    __syncthreads();                                                             \
  }

  for (int tp = 0; tp < 14; ++tp) {
    PV_STEP(bra, brb, 2 * tp, 0);
    PV_STEP(brb, bra, 2 * tp + 1, 1);
  }
#undef PV_STEP

  u16* out = Ppart + (long)(b * PVSPLIT + z) * NP * DO_;
#pragma unroll
  for (int m = 0; m < 4; ++m) {
#pragma unroll
    for (int n = 0; n < 8; ++n) {
      int col = wave * 128 + n * 16 + lr;
#pragma unroll
      for (int j = 0; j < 4; ++j) {
        int row = m0 + m * 16 + kg * 4 + j;
        out[(long)row * DO_ + col] = f2bf(acc[m][n][j]);
      }
    }
  }
}

// ---------- small kernels ----------
__global__ void k_transpose_cast(const float* __restrict__ in, u16* __restrict__ out,
                                 int R, int C, int Cp, int out_ld,
                                 long in_bs, long out_bs) {
  __shared__ float t[32][33];
  long b = blockIdx.z;
  int c0 = blockIdx.x * 32, r0 = blockIdx.y * 32;
  int tx = threadIdx.x, ty = threadIdx.y;
#pragma unroll
  for (int i = 0; i < 32; i += 8) {
    int r = r0 + ty + i, c = c0 + tx;
    t[ty + i][tx] = (r < R && c < C) ? in[b * in_bs + (long)r * C + c] : 0.f;
  }
  __syncthreads();
#pragma unroll
  for (int i = 0; i < 32; i += 8) {
    int c = c0 + ty + i, r = r0 + tx;
    if (c < Cp && r < R)
      out[b * out_bs + (long)c * out_ld + r] = f2bf(t[tx][ty + i]);
  }
}

__global__ void k_cast_pad(const float* __restrict__ in, u16* __restrict__ out,
                           int Cin, int Cout, long in_bs, long out_bs) {
  int c = blockIdx.x * 256 + threadIdx.x;
  int r = blockIdx.y;
  long b = blockIdx.z;
  if (c >= Cout) return;
  out[b * out_bs + (long)r * Cout + c] =
      (c < Cin) ? f2bf(in[b * in_bs + (long)r * Cin + c]) : (u16)0;
}

// weights: wruh[1024][512] (h-halves of wr,wu); wruxc[1536][512] (x-halves of
// wr,wu,wc); wch[512][512] (h-half of wc)
__global__ void k_build_w(const float* __restrict__ wr_, const float* __restrict__ wu_,
                          const float* __restrict__ wc_,
                          u16* __restrict__ wruh, u16* __restrict__ wruxc,
                          u16* __restrict__ wch) {
  int k = blockIdx.x * 256 + threadIdx.x;  // 0..511
  int m = blockIdx.y;                      // 0..3071
  if (k >= 512) return;
  if (m < 1024) {
    const float* src = (m < 512) ? wr_ : wu_;
    wruh[m * 512 + k] = f2bf(src[(m & 511) * 1024 + 512 + k]);
  } else if (m < 2560) {
    int n = m - 1024;
    const float* src = (n < 512) ? wr_ : ((n < 1024) ? wu_ : wc_);
    wruxc[n * 512 + k] = f2bf(src[(n & 511) * 1024 + k]);
  } else {
    int n = m - 2560;
    wch[n * 512 + k] = f2bf(wc_[n * 1024 + 512 + k]);
  }
}

__global__ void k_bias_ru(const float* __restrict__ br_, const float* __restrict__ bu_,
                          float* __restrict__ bias) {
  int i = blockIdx.x * 256 + threadIdx.x;
  if (i < 1024) bias[i] = (i < 512) ? br_[i] : bu_[i - 512];
}

__global__ void k_invz(const float* __restrict__ Zp, float* __restrict__ invZ) {
  int t = blockIdx.x * 256 + threadIdx.x;
  if (t >= NB * NP) return;
  int b = t / NP, q = t - b * NP;
  const float* base = Zp + (long)b * 49 * NP + q;
  float s = 0.f;
#pragma unroll
  for (int nb = 0; nb < 49; ++nb) s += base[(long)nb * NP];
  invZ[t] = 1.f / s;
}

__global__ void k_reduce_mem(const u16* __restrict__ Ppart, const float* __restrict__ invZ,
                             u16* __restrict__ memTb) {
  long t = (long)blockIdx.x * 256 + threadIdx.x;   // uint4 index (8 bf16)
  const long bs = (long)NP * DO_;
  if (t >= (long)NB * bs / 8) return;
  long flat = t * 8;
  int b = (int)(flat / bs);
  long r = flat - (long)b * bs;
  int q = (int)(r / DO_);
  float s[8];
#pragma unroll
  for (int e = 0; e < 8; ++e) s[e] = 0.f;
#pragma unroll
  for (int z = 0; z < PVSPLIT; ++z) {
    uint4 v = *(const uint4*)&Ppart[(long)(b * PVSPLIT + z) * bs + r];
    s[0] += bf2f((u16)(v.x & 0xffff)); s[1] += bf2f((u16)(v.x >> 16));
    s[2] += bf2f((u16)(v.y & 0xffff)); s[3] += bf2f((u16)(v.y >> 16));
    s[4] += bf2f((u16)(v.z & 0xffff)); s[5] += bf2f((u16)(v.z >> 16));
    s[6] += bf2f((u16)(v.w & 0xffff)); s[7] += bf2f((u16)(v.w >> 16));
  }
  float iz = invZ[b * NP + q];
  uint4 o;
  o.x = (unsigned)f2bf(s[0] * iz) | ((unsigned)f2bf(s[1] * iz) << 16);
  o.y = (unsigned)f2bf(s[2] * iz) | ((unsigned)f2bf(s[3] * iz) << 16);
  o.z = (unsigned)f2bf(s[4] * iz) | ((unsigned)f2bf(s[5] * iz) << 16);
  o.w = (unsigned)f2bf(s[6] * iz) | ((unsigned)f2bf(s[7] * iz) << 16);
  *(uint4*)&memTb[(long)b * bs + r] = o;
}

__global__ void k_out_q(const float* __restrict__ Qfin, float* __restrict__ dout) {
  __shared__ float t[32][33];
  long b = blockIdx.z;
  int q0 = blockIdx.x * 32, ch0 = blockIdx.y * 32;
  int tx = threadIdx.x, ty = threadIdx.y;
#pragma unroll
  for (int i = 0; i < 32; i += 8)
    t[ty + i][tx] = Qfin[b * ((long)NP * 512) + (long)(q0 + ty + i) * 512 + ch0 + tx];
  __syncthreads();
#pragma unroll
  for (int i = 0; i < 32; i += 8) {
    int ch = ch0 + ty + i, q = q0 + tx;
    if (q < HW)
      dout[b * ((long)1024 * HW) + (long)ch * HW + q] = t[tx][ty + i];
  }
}

__global__ void k_copy_q0(const float4* __restrict__ src, float4* __restrict__ dst) {
  int idx = blockIdx.x * 256 + threadIdx.x;
  long b = blockIdx.z;
  const long n4 = (long)DO_ * HW / 4;  // 199680
  if (idx < n4)
    dst[b * ((long)1024 * HW / 4) + n4 + idx] = src[b * n4 + idx];
}

// ---------- host ----------
extern "C" void kernel_launch(void* const* d_in, const int* in_sizes, int n_in,
                              void* d_out, int out_size, void* d_ws, size_t ws_size,
                              hipStream_t stream) {
  const float* m_in  = (const float*)d_in[0];
  const float* m_out = (const float*)d_in[1];
  const float* q_in  = (const float*)d_in[2];
  const float* q_out = (const float*)d_in[3];
  const float* wr    = (const float*)d_in[4];
  const float* br    = (const float*)d_in[5];
  const float* wu    = (const float*)d_in[6];
  const float* bu    = (const float*)d_in[7];
  const float* wc    = (const float*)d_in[8];
  const float* bc    = (const float*)d_in[9];
  float* dout = (float*)d_out;

  // workspace layout
  char* p = (char*)d_ws;
  size_t off = 0;
  auto alloc = [&](size_t bytes) { void* r = p + off; off += (bytes + 255) & ~(size_t)255; return r; };
  u16*   miT    = (u16*)alloc((size_t)NB * KP * DE * 2);       // [b][k][128]
  u16*   qiT    = (u16*)alloc((size_t)NB * NP * DE * 2);       // [b][q][128]
  u16*   Pt     = (u16*)alloc((size_t)NB * NP * KP * 2);       // [b][q][k]
  float* invZ   = (float*)alloc((size_t)NB * NP * 4);
  u16*   moutb  = (u16*)alloc((size_t)NB * DO_ * KP * 2);      // [b][o][k]
  u16*   memTb  = (u16*)alloc((size_t)NB * NP * DO_ * 2);      // [b][q][o]
  // chru,U,XRb,Qfin contiguous: pv partials (28 * NP*DO_*2 = 47.7MB) alias
  // this span (all four dead until after k_reduce_mem).
  u16*   chru   = (u16*)alloc((size_t)NB * NP * 1024 * 2);     // [b][q][r|u]
  u16*   U      = (u16*)alloc((size_t)NB * NP * DO_ * 2);
  u16*   XRb    = (u16*)alloc((size_t)NB * NP * 1024 * 2);
  float* Qfin   = (float*)alloc((size_t)NB * NP * DO_ * 4);
  u16*   XRa    = (u16*)alloc((size_t)NB * NP * 1024 * 2);     // [b][q][x|rh]
  u16*   Cx     = (u16*)alloc((size_t)NB * NP * 512 * 2);      // cand X-partial
  u16*   wruh   = (u16*)alloc((size_t)1024 * 512 * 2);
  u16*   wruxc  = (u16*)alloc((size_t)1536 * 512 * 2);
  u16*   wch    = (u16*)alloc((size_t)512 * 512 * 2);
  float* biasru = (float*)alloc((size_t)1024 * 4);
  u16*   Ppart  = (u16*)chru;      // [NB*PVSPLIT][NP][DO_] bf16, alias
  float* Zp     = (float*)memTb;   // [NB][49][NP] f32, alias (dead before memTb)
  if (off > ws_size) return;

  // --- prep: weights ---
  k_build_w<<<dim3(2, 3072), 256, 0, stream>>>(wr, wu, wc, wruh, wruxc, wch);
  k_bias_ru<<<dim3(4), 256, 0, stream>>>(br, bu, biasru);
  // --- prep: inputs ---
  k_cast_pad<<<dim3(25, 512, NB), 256, 0, stream>>>(
      m_out, moutb, THW, KP, (long)DO_ * THW, (long)DO_ * KP);
  k_transpose_cast<<<dim3(196, 4, NB), dim3(32, 8), 0, stream>>>(
      m_in, miT, DE, THW, KP, DE, (long)DE * THW, (long)KP * DE);
  k_transpose_cast<<<dim3(52, 4, NB), dim3(32, 8), 0, stream>>>(
      q_in, qiT, DE, HW, NP, DE, (long)DE * HW, (long)NP * DE);
  k_transpose_cast<<<dim3(52, 16, NB), dim3(32, 8), 0, stream>>>(
      q_out, XRa, DO_, HW, NP, 1024, (long)DO_ * HW, (long)NP * 1024);

  // --- attention scores: Pt = exp(S/sqrt(De)); Zp row-sum partials ---
  gk_scores<<<dim3(13, 49, NB), 256, 0, stream>>>(
      qiT, miT, DE, DE, DE, (long)NP * DE, (long)KP * DE,
      Zp, (long)49 * NP, 0, Pt, (long)NP * KP, KP, nullptr, 0,
      nullptr, 0, nullptr, 0, nullptr, 0, nullptr, 0, THW, 0.08838834764831845f);
  k_invz<<<dim3(26), 256, 0, stream>>>(Zp, invZ);

  // --- mem: Ppart = Pt @ moutb^T (BN=512, split-K x7, XCD-pinned, drain) ---
  gemm_pv<<<dim3(728), 256, 0, stream>>>(Pt, moutb, Ppart);
  k_reduce_mem<<<dim3(1664), 256, 0, stream>>>(Ppart, invZ, memTb);

  // --- Chru(bf16) = memT @ Wruh^T + [br;bu] ---
  gk_chru<<<dim3(26, 8, NB), 256, 0, stream>>>(
      memTb, wruh, DO_, DO_, DO_, (long)NP * DO_, 0,
      nullptr, 0, 0, chru, (long)NP * 1024, 1024, nullptr, 0,
      biasru, 0, nullptr, 0, nullptr, 0, nullptr, 0, 0, 0.f);

  // --- GRU layers ---
  u16* xr[2] = {XRa, XRb};
  for (int l = 0; l < PROP; ++l) {
    u16* cur = xr[l & 1];
    u16* nxt = xr[(l + 1) & 1];
    // gates r,u + cand-X partial: N=1536 over [Wr_x|Wu_x|Wc_x]
    gk_gates<<<dim3(26, 12, NB), 256, 0, stream>>>(
        cur, wruxc, DO_, 1024, DO_, (long)NP * 1024, 0,
        U, (long)NP * DO_, DO_, cur, (long)NP * 1024, 1024,
        Cx, (long)NP * 512,
        chru, (long)NP * 1024, memTb, (long)NP * DO_, nullptr, 0,
        nullptr, 0, 0, 0.f);
    // candidate (K=512 RH half) + GRU update
    gk_cand<<<dim3(26, 4, NB), 256, 0, stream>>>(
        cur + 512, wch, DO_, 1024, DO_, (long)NP * 1024, 0,
        (l == PROP - 1) ? (void*)Qfin : nullptr, (long)NP * DO_, DO_,
        nxt, (long)NP * 1024, 1024, nullptr, 0,
        bc, 0, U, (long)NP * DO_, memTb, (long)NP * DO_,
        Cx, (long)NP * 512, 0, 0.f);
  }

  // --- outputs ---
  k_out_q<<<dim3(49, 16, NB), dim3(32, 8), 0, stream>>>(Qfin, dout);
  k_copy_q0<<<dim3(780, 1, NB), 256, 0, stream>>>((const float4*)q_out, (float4*)dout);
}